// Round 3
// baseline (604.864 us; speedup 1.0000x reference)
//
#include <hip/hip_runtime.h>
#include <hip/hip_bf16.h>

// NOTE (r2 finding): inputs and output are FLOAT32 (reference dtype), not bf16.
// Internal pipeline uses bf16 MFMA with hi/lo splitting for the q/k path.

typedef unsigned short u16;
typedef __attribute__((ext_vector_type(4))) float          floatx4;
typedef __attribute__((ext_vector_type(8))) short          shortx8;
typedef __attribute__((ext_vector_type(4))) unsigned short ushortx4;

#define EMB   768
#define SEQ   2048
#define NHEAD 12
#define HDIM  64
#define RPM   4096   // rows per modal (B*N)
#define NROW  8192   // total rows (2 modals)
#define NUNIT 48     // modal*B*H units
#define LDA   40     // padded LDS stride (bf16 elems) for GEMM tiles (BK=32)
#define LDK   72     // padded LDS stride for attention tiles (64 cols)

__device__ __forceinline__ float bf2f(u16 h) {
  union { unsigned u; float f; } v; v.u = ((unsigned)h) << 16; return v.f;
}
__device__ __forceinline__ u16 f2bf(float f) {
  union { float f; unsigned u; } v; v.f = f;
  unsigned r = v.u + 0x7fffu + ((v.u >> 16) & 1u);  // RNE
  return (u16)(r >> 16);
}

// ---------------- Kernel 1: LayerNorm (fp32 in) + hi/lo bf16 split ----------------
__global__ __launch_bounds__(256) void k_ln(
    const float* __restrict__ x1, const float* __restrict__ x2,
    const float* __restrict__ g1, const float* __restrict__ b1,
    const float* __restrict__ g2, const float* __restrict__ b2,
    u16* __restrict__ xn_hi, u16* __restrict__ xn_lo)
{
  int row = blockIdx.x;                 // 0..8191, modal-major
  int modal = row >> 12;
  const float* x = modal ? x2 : x1;
  const float* g = modal ? g2 : g1;
  const float* bb = modal ? b2 : b1;
  int r = row & (RPM - 1);
  const float* xr = x + (size_t)r * EMB;
  int t = threadIdx.x;
  float v0 = xr[t], v1 = xr[t + 256], v2 = xr[t + 512];
  float s = v0 + v1 + v2;
  float s2 = v0 * v0 + v1 * v1 + v2 * v2;
  #pragma unroll
  for (int m = 1; m < 64; m <<= 1) { s += __shfl_xor(s, m); s2 += __shfl_xor(s2, m); }
  __shared__ float ls[4], ls2[4];
  int w = t >> 6;
  if ((t & 63) == 0) { ls[w] = s; ls2[w] = s2; }
  __syncthreads();
  s = ls[0] + ls[1] + ls[2] + ls[3];
  s2 = ls2[0] + ls2[1] + ls2[2] + ls2[3];
  float mu = s * (1.0f / EMB);
  float var = s2 * (1.0f / EMB) - mu * mu;
  float rs = rsqrtf(var + 1e-5f);
  size_t base = (size_t)row * EMB;
  float vv[3] = { v0, v1, v2 };
  #pragma unroll
  for (int i = 0; i < 3; ++i) {
    int e = t + i * 256;
    float xn = (vv[i] - mu) * rs * g[e] + bb[e];
    u16 h = f2bf(xn);
    xn_hi[base + e] = h;
    xn_lo[base + e] = f2bf(xn - bf2f(h));
  }
}

// ---------------- Kernel 2: QKV GEMM (split-A, split-W, permuted W) ----------------
// grid (32 row-tiles, 18 col-tiles, 2 modals), 256 thr. Tile 128x128, BK=32.
__global__ __launch_bounds__(256) void k_qkv(
    const u16* __restrict__ xn_hi, const u16* __restrict__ xn_lo,
    const float* __restrict__ wq1, const float* __restrict__ bq1,
    const float* __restrict__ wq2, const float* __restrict__ bq2,
    u16* __restrict__ q_hi, u16* __restrict__ q_lo,
    u16* __restrict__ k_hi, u16* __restrict__ k_lo,
    u16* __restrict__ vT)
{
  int mt = blockIdx.x, ntile = blockIdx.y, modal = blockIdx.z;
  const float* W  = modal ? wq2 : wq1;
  const float* BQ = modal ? bq2 : bq1;
  int typ = ntile / 6;            // 0=q 1=k 2=v  (permuted column order)
  int hd0 = (ntile % 6) * 128;    // hd = h*64+d block start

  __shared__ u16 As_hi[128 * LDA], As_lo[128 * LDA], Wh[128 * LDA], Wl[128 * LDA];

  int tid = threadIdx.x, lane = tid & 63, w = tid >> 6;
  int wm = (w >> 1) * 64, wn = (w & 1) * 64;
  int lc = lane & 15, lq = lane >> 4;

  floatx4 acc[4][4] = {};
  size_t arow0 = (size_t)(modal * RPM + mt * 128) * EMB;

  for (int k0 = 0; k0 < EMB; k0 += 32) {
    // A tiles: 128 rows x 32 cols of u16, 512 chunks of 8
    #pragma unroll
    for (int i = 0; i < 2; ++i) {
      int c = tid + i * 256;
      int rr = c >> 2, cc = (c & 3) * 8;
      *(shortx8*)&As_hi[rr * LDA + cc] = *(const shortx8*)(xn_hi + arow0 + (size_t)rr * EMB + k0 + cc);
      *(shortx8*)&As_lo[rr * LDA + cc] = *(const shortx8*)(xn_lo + arow0 + (size_t)rr * EMB + k0 + cc);
    }
    // W tile: 128 rows x 32 cols of fp32 -> hi/lo bf16 split; 1024 float4 chunks
    #pragma unroll
    for (int i = 0; i < 4; ++i) {
      int c = tid + i * 256;
      int rr = c >> 3, cc = (c & 7) * 4;
      int j = (hd0 + rr) * 3 + typ;     // permuted weight row
      floatx4 wv = *(const floatx4*)(W + (size_t)j * EMB + k0 + cc);
      ushortx4 h, l;
      #pragma unroll
      for (int m = 0; m < 4; ++m) {
        h[m] = f2bf(wv[m]);
        l[m] = f2bf(wv[m] - bf2f(h[m]));
      }
      *(ushortx4*)&Wh[rr * LDA + cc] = h;
      if (typ != 2) *(ushortx4*)&Wl[rr * LDA + cc] = l;
    }
    __syncthreads();
    shortx8 ah[4], al[4], wh[4], wl[4];
    #pragma unroll
    for (int i = 0; i < 4; ++i) {
      ah[i] = *(const shortx8*)&As_hi[(wm + i * 16 + lc) * LDA + lq * 8];
      al[i] = *(const shortx8*)&As_lo[(wm + i * 16 + lc) * LDA + lq * 8];
      wh[i] = *(const shortx8*)&Wh[(wn + i * 16 + lc) * LDA + lq * 8];
      if (typ != 2) wl[i] = *(const shortx8*)&Wl[(wn + i * 16 + lc) * LDA + lq * 8];
    }
    #pragma unroll
    for (int i = 0; i < 4; ++i)
      #pragma unroll
      for (int jn = 0; jn < 4; ++jn) {
        acc[i][jn] = __builtin_amdgcn_mfma_f32_16x16x32_bf16(ah[i], wh[jn], acc[i][jn], 0, 0, 0);
        acc[i][jn] = __builtin_amdgcn_mfma_f32_16x16x32_bf16(al[i], wh[jn], acc[i][jn], 0, 0, 0);
        if (typ != 2)
          acc[i][jn] = __builtin_amdgcn_mfma_f32_16x16x32_bf16(ah[i], wl[jn], acc[i][jn], 0, 0, 0);
      }
    __syncthreads();
  }

  // epilogue: C/D layout col=lane&15, row=lq*4+r
  #pragma unroll
  for (int i = 0; i < 4; ++i) {
    int mrow0 = mt * 128 + wm + i * 16 + lq * 4;   // row within modal [0,4096)
    #pragma unroll
    for (int jn = 0; jn < 4; ++jn) {
      int colp = hd0 + wn + jn * 16 + lc;          // hd index [0,768)
      int h = colp >> 6, d = colp & 63;
      float bias = BQ[colp * 3 + typ];
      #pragma unroll
      for (int r = 0; r < 4; ++r) {
        int mrow = mrow0 + r;
        int b = mrow >> 11, nq = mrow & (SEQ - 1);
        int u = modal * 24 + b * 12 + h;
        float val = acc[i][jn][r] + bias;
        if (typ == 0) {
          size_t o = ((size_t)u * SEQ + nq) * HDIM + d;
          u16 hh = f2bf(val); q_hi[o] = hh; q_lo[o] = f2bf(val - bf2f(hh));
        } else if (typ == 1) {
          size_t o = ((size_t)u * SEQ + nq) * HDIM + d;
          u16 hh = f2bf(val); k_hi[o] = hh; k_lo[o] = f2bf(val - bf2f(hh));
        } else {
          vT[((size_t)u * HDIM + d) * SEQ + nq] = f2bf(val);
        }
      }
    }
  }
}

// ---------------- Kernel 3: flash attention (all-internal bf16) ----------------
// grid (32 q-tiles, 48 units), 256 thr. Each wave owns 16 q-rows; K-chunk 64.
__global__ __launch_bounds__(256) void k_attn(
    const u16* __restrict__ q_hi, const u16* __restrict__ q_lo,
    const u16* __restrict__ k_hi, const u16* __restrict__ k_lo,
    const u16* __restrict__ vT, u16* __restrict__ attn_out)
{
  int qt = blockIdx.x, u = blockIdx.y;
  __shared__ u16 Kh[64 * LDK], Kl[64 * LDK], Vs[64 * LDK];
  __shared__ u16 Ps[4][16 * LDK];

  int tid = threadIdx.x, lane = tid & 63, w = tid >> 6;
  int lc = lane & 15, lq = lane >> 4;

  // Q fragments (A-layout: m=lane&15, k=lq*8+j), hi+lo, 2 k-slices of d
  size_t qbase = ((size_t)u * SEQ + qt * 64 + w * 16 + lc) * HDIM;
  shortx8 qh[2], ql[2];
  qh[0] = *(const shortx8*)(q_hi + qbase + lq * 8);
  qh[1] = *(const shortx8*)(q_hi + qbase + 32 + lq * 8);
  ql[0] = *(const shortx8*)(q_lo + qbase + lq * 8);
  ql[1] = *(const shortx8*)(q_lo + qbase + 32 + lq * 8);

  floatx4 O[4] = {};
  float mrow[4] = { -1e30f, -1e30f, -1e30f, -1e30f };
  float lrow[4] = { 0.f, 0.f, 0.f, 0.f };
  const float Cs = 11.5415603271f;  // 8 * log2(e): logits in log2 domain

  for (int kc = 0; kc < SEQ; kc += 64) {
    #pragma unroll
    for (int i = 0; i < 2; ++i) {
      int c = tid + i * 256;            // 512 chunks of 8 (64 rows x 64 cols)
      int rr = c >> 3, cc = (c & 7) * 8;
      *(shortx8*)&Kh[rr * LDK + cc] = *(const shortx8*)(k_hi + ((size_t)u * SEQ + kc + rr) * HDIM + cc);
      *(shortx8*)&Kl[rr * LDK + cc] = *(const shortx8*)(k_lo + ((size_t)u * SEQ + kc + rr) * HDIM + cc);
      *(shortx8*)&Vs[rr * LDK + cc] = *(const shortx8*)(vT + ((size_t)u * HDIM + rr) * SEQ + kc + cc);
    }
    __syncthreads();

    floatx4 S[4] = {};
    #pragma unroll
    for (int nt = 0; nt < 4; ++nt)
      #pragma unroll
      for (int ks = 0; ks < 2; ++ks) {
        shortx8 kf = *(const shortx8*)&Kh[(nt * 16 + lc) * LDK + ks * 32 + lq * 8];
        shortx8 lf = *(const shortx8*)&Kl[(nt * 16 + lc) * LDK + ks * 32 + lq * 8];
        S[nt] = __builtin_amdgcn_mfma_f32_16x16x32_bf16(qh[ks], kf, S[nt], 0, 0, 0);
        S[nt] = __builtin_amdgcn_mfma_f32_16x16x32_bf16(ql[ks], kf, S[nt], 0, 0, 0);
        S[nt] = __builtin_amdgcn_mfma_f32_16x16x32_bf16(qh[ks], lf, S[nt], 0, 0, 0);
      }

    // online softmax (per-wave rows lq*4+r); stats over 16 lanes sharing lq
    float mc[4];
    #pragma unroll
    for (int r = 0; r < 4; ++r)
      mc[r] = fmaxf(fmaxf(S[0][r], S[1][r]), fmaxf(S[2][r], S[3][r]));
    #pragma unroll
    for (int m = 1; m < 16; m <<= 1)
      #pragma unroll
      for (int r = 0; r < 4; ++r) mc[r] = fmaxf(mc[r], __shfl_xor(mc[r], m));
    float alpha[4];
    #pragma unroll
    for (int r = 0; r < 4; ++r) {
      float mn = fmaxf(mrow[r], mc[r] * Cs);
      alpha[r] = exp2f(mrow[r] - mn);
      mrow[r] = mn;
    }
    float psum[4] = { 0.f, 0.f, 0.f, 0.f };
    #pragma unroll
    for (int nt = 0; nt < 4; ++nt)
      #pragma unroll
      for (int r = 0; r < 4; ++r) {
        float e = exp2f(S[nt][r] * Cs - mrow[r]);
        psum[r] += e;
        Ps[w][(lq * 4 + r) * LDK + nt * 16 + lc] = f2bf(e);
      }
    #pragma unroll
    for (int m = 1; m < 16; m <<= 1)
      #pragma unroll
      for (int r = 0; r < 4; ++r) psum[r] += __shfl_xor(psum[r], m);
    #pragma unroll
    for (int r = 0; r < 4; ++r) lrow[r] = lrow[r] * alpha[r] + psum[r];
    #pragma unroll
    for (int nt = 0; nt < 4; ++nt)
      #pragma unroll
      for (int r = 0; r < 4; ++r) O[nt][r] *= alpha[r];

    __syncthreads();  // Ps visible

    #pragma unroll
    for (int ks = 0; ks < 2; ++ks) {
      shortx8 pf = *(const shortx8*)&Ps[w][lc * LDK + ks * 32 + lq * 8];
      #pragma unroll
      for (int nt = 0; nt < 4; ++nt) {
        shortx8 vf = *(const shortx8*)&Vs[(nt * 16 + lc) * LDK + ks * 32 + lq * 8];
        O[nt] = __builtin_amdgcn_mfma_f32_16x16x32_bf16(pf, vf, O[nt], 0, 0, 0);
      }
    }
    __syncthreads();
  }

  int modal = u / 24, b = (u / 12) & 1, h = u % 12;
  #pragma unroll
  for (int nt = 0; nt < 4; ++nt)
    #pragma unroll
    for (int r = 0; r < 4; ++r) {
      int qrow = qt * 64 + w * 16 + lq * 4 + r;
      size_t o = ((size_t)(modal * RPM + b * SEQ + qrow)) * EMB + h * 64 + nt * 16 + lc;
      attn_out[o] = f2bf(O[nt][r] / lrow[r]);
    }
}

// ---------------- Kernel 4: proj GEMM + bias + fp32 residual -> fp32 out ----------------
// grid (32 row-tiles, 6 col-tiles, 2 modals)
__global__ __launch_bounds__(256) void k_proj(
    const u16* __restrict__ ao,
    const float* __restrict__ x1, const float* __restrict__ x2,
    const float* __restrict__ wp1, const float* __restrict__ bp1,
    const float* __restrict__ wp2, const float* __restrict__ bp2,
    float* __restrict__ out)
{
  int mt = blockIdx.x, ntile = blockIdx.y, modal = blockIdx.z;
  const float* W  = modal ? wp2 : wp1;
  const float* BP = modal ? bp2 : bp1;
  const float* x  = modal ? x2 : x1;

  __shared__ u16 As[128 * LDA], Ws[128 * LDA];
  int tid = threadIdx.x, lane = tid & 63, w = tid >> 6;
  int wm = (w >> 1) * 64, wn = (w & 1) * 64;
  int lc = lane & 15, lq = lane >> 4;

  floatx4 acc[4][4] = {};
  size_t arow0 = (size_t)(modal * RPM + mt * 128) * EMB;
  int col0 = ntile * 128;

  for (int k0 = 0; k0 < EMB; k0 += 32) {
    #pragma unroll
    for (int i = 0; i < 2; ++i) {
      int c = tid + i * 256;
      int rr = c >> 2, cc = (c & 3) * 8;
      *(shortx8*)&As[rr * LDA + cc] = *(const shortx8*)(ao + arow0 + (size_t)rr * EMB + k0 + cc);
    }
    #pragma unroll
    for (int i = 0; i < 4; ++i) {
      int c = tid + i * 256;
      int rr = c >> 3, cc = (c & 7) * 4;
      floatx4 wv = *(const floatx4*)(W + (size_t)(col0 + rr) * EMB + k0 + cc);
      ushortx4 h;
      #pragma unroll
      for (int m = 0; m < 4; ++m) h[m] = f2bf(wv[m]);
      *(ushortx4*)&Ws[rr * LDA + cc] = h;
    }
    __syncthreads();
    shortx8 af[4], wf[4];
    #pragma unroll
    for (int i = 0; i < 4; ++i) {
      af[i] = *(const shortx8*)&As[(wm + i * 16 + lc) * LDA + lq * 8];
      wf[i] = *(const shortx8*)&Ws[(wn + i * 16 + lc) * LDA + lq * 8];
    }
    #pragma unroll
    for (int i = 0; i < 4; ++i)
      #pragma unroll
      for (int jn = 0; jn < 4; ++jn)
        acc[i][jn] = __builtin_amdgcn_mfma_f32_16x16x32_bf16(af[i], wf[jn], acc[i][jn], 0, 0, 0);
    __syncthreads();
  }

  #pragma unroll
  for (int i = 0; i < 4; ++i) {
    int mrow0 = mt * 128 + wm + i * 16 + lq * 4;
    #pragma unroll
    for (int jn = 0; jn < 4; ++jn) {
      int col = col0 + wn + jn * 16 + lc;
      float bias = BP[col];
      #pragma unroll
      for (int r = 0; r < 4; ++r) {
        int mrow = mrow0 + r;
        float val = acc[i][jn][r] + bias + x[(size_t)mrow * EMB + col];
        out[((size_t)(modal * RPM + mrow)) * EMB + col] = val;
      }
    }
  }
}

extern "C" void kernel_launch(void* const* d_in, const int* in_sizes, int n_in,
                              void* d_out, int out_size, void* d_ws, size_t ws_size,
                              hipStream_t stream) {
  const float* modal1 = (const float*)d_in[0];
  const float* modal2 = (const float*)d_in[1];
  const float* ln1_g  = (const float*)d_in[2];
  const float* ln1_b  = (const float*)d_in[3];
  const float* w_qkv1 = (const float*)d_in[4];
  const float* b_qkv1 = (const float*)d_in[5];
  const float* w_proj1= (const float*)d_in[6];
  const float* b_proj1= (const float*)d_in[7];
  const float* ln2_g  = (const float*)d_in[8];
  const float* ln2_b  = (const float*)d_in[9];
  const float* w_qkv2 = (const float*)d_in[10];
  const float* b_qkv2 = (const float*)d_in[11];
  const float* w_proj2= (const float*)d_in[12];
  const float* b_proj2= (const float*)d_in[13];
  float* out = (float*)d_out;

  const size_t BUFE = (size_t)NROW * EMB;  // 6291456 elems per u16 buffer
  u16* xn_hi = (u16*)d_ws;
  u16* xn_lo = xn_hi + BUFE;
  u16* q_hi  = xn_lo + BUFE;
  u16* q_lo  = q_hi + BUFE;
  u16* k_hi  = q_lo + BUFE;
  u16* k_lo  = k_hi + BUFE;
  u16* vT    = k_lo + BUFE;
  u16* attn  = xn_hi;  // reuse: xn consumed by k_qkv before k_attn writes

  k_ln<<<NROW, 256, 0, stream>>>(modal1, modal2, ln1_g, ln1_b, ln2_g, ln2_b, xn_hi, xn_lo);
  dim3 g2(32, 18, 2);
  k_qkv<<<g2, 256, 0, stream>>>(xn_hi, xn_lo, w_qkv1, b_qkv1, w_qkv2, b_qkv2,
                                q_hi, q_lo, k_hi, k_lo, vT);
  dim3 g3(32, 48);
  k_attn<<<g3, 256, 0, stream>>>(q_hi, q_lo, k_hi, k_lo, vT, attn);
  dim3 g4(32, 6, 2);
  k_proj<<<g4, 256, 0, stream>>>(attn, modal1, modal2, w_proj1, b_proj1,
                                 w_proj2, b_proj2, out);
}

// Round 4
// 407.315 us; speedup vs baseline: 1.4850x; 1.4850x over previous
//
#include <hip/hip_runtime.h>
#include <hip/hip_bf16.h>

// r2: I/O is fp32. r3: passed 605us, k_attn 288us VALU-bound (1650 VALU cyc/wave-iter).
// r4: 2 q-tiles/wave, builtin exp2, ds_swizzle max-reduce, ones-column MFMA for l,
//     trunc P-store, 2 barriers/iter, pre-split weights (prep kernels).

typedef unsigned short u16;
typedef unsigned int   u32;
typedef __attribute__((ext_vector_type(4))) float          floatx4;
typedef __attribute__((ext_vector_type(8))) short          shortx8;

#define EMB   768
#define SEQ   2048
#define NHEAD 12
#define HDIM  64
#define RPM   4096   // rows per modal (B*N)
#define NROW  8192   // total rows (2 modals)
#define NUNIT 48     // modal*B*H units
#define LDA   40     // padded LDS stride (bf16) for GEMM tiles (BK=32)
#define LDK   72     // padded LDS stride for attention tiles (64 cols)

__device__ __forceinline__ float bf2f(u16 h) {
  union { u32 u; float f; } v; v.u = ((u32)h) << 16; return v.f;
}
__device__ __forceinline__ u16 f2bf(float f) {            // RNE
  union { float f; u32 u; } v; v.f = f;
  u32 r = v.u + 0x7fffu + ((v.u >> 16) & 1u);
  return (u16)(r >> 16);
}
__device__ __forceinline__ u16 f2bf_tr(float f) {         // truncate (P in [0,1])
  union { float f; u32 u; } v; v.f = f;
  return (u16)(v.u >> 16);
}
__device__ __forceinline__ float swz_max16(float v) {     // max over 16-lane group
  union { float f; int i; } a;
  a.f = v; a.i = __builtin_amdgcn_ds_swizzle(a.i, 0x041F); v = fmaxf(v, a.f);
  a.f = v; a.i = __builtin_amdgcn_ds_swizzle(a.i, 0x081F); v = fmaxf(v, a.f);
  a.f = v; a.i = __builtin_amdgcn_ds_swizzle(a.i, 0x101F); v = fmaxf(v, a.f);
  a.f = v; a.i = __builtin_amdgcn_ds_swizzle(a.i, 0x201F); v = fmaxf(v, a.f);
  return v;
}

// ---------------- prep: split qkv weights fp32 -> bf16 hi/lo, permuted ----------------
// out layout: row R = modal*2304 + typ*768 + hd  (source j = hd*3 + typ)
__global__ __launch_bounds__(256) void prep_wq(
    const float* __restrict__ wq1, const float* __restrict__ wq2,
    u16* __restrict__ wh, u16* __restrict__ wl)
{
  int bx = blockIdx.x;                  // 0..4607
  int modal = bx / 2304, rowp = bx % 2304;
  int typ = rowp / 768, hd = rowp % 768;
  const float* W = (modal ? wq2 : wq1) + (size_t)(hd * 3 + typ) * EMB;
  size_t dst = (size_t)bx * EMB;
  int t = threadIdx.x;
  #pragma unroll
  for (int i = 0; i < 3; ++i) {
    int e = t + i * 256;
    float v = W[e];
    u16 h = f2bf(v);
    wh[dst + e] = h;
    wl[dst + e] = f2bf(v - bf2f(h));
  }
}

// prep: w_proj fp32 -> bf16 hi only
__global__ __launch_bounds__(256) void prep_wp(
    const float* __restrict__ wp1, const float* __restrict__ wp2,
    u16* __restrict__ wh)
{
  int bx = blockIdx.x;                  // 0..1535
  int modal = bx / 768, row = bx % 768;
  const float* W = (modal ? wp2 : wp1) + (size_t)row * EMB;
  size_t dst = (size_t)bx * EMB;
  int t = threadIdx.x;
  #pragma unroll
  for (int i = 0; i < 3; ++i) {
    int e = t + i * 256;
    wh[dst + e] = f2bf(W[e]);
  }
}

// ---------------- Kernel 1: LayerNorm (fp32 in) + hi/lo bf16 split ----------------
__global__ __launch_bounds__(256) void k_ln(
    const float* __restrict__ x1, const float* __restrict__ x2,
    const float* __restrict__ g1, const float* __restrict__ b1,
    const float* __restrict__ g2, const float* __restrict__ b2,
    u16* __restrict__ xn_hi, u16* __restrict__ xn_lo)
{
  int row = blockIdx.x;                 // 0..8191, modal-major
  int modal = row >> 12;
  const float* x = modal ? x2 : x1;
  const float* g = modal ? g2 : g1;
  const float* bb = modal ? b2 : b1;
  int r = row & (RPM - 1);
  const float* xr = x + (size_t)r * EMB;
  int t = threadIdx.x;
  float v0 = xr[t], v1 = xr[t + 256], v2 = xr[t + 512];
  float s = v0 + v1 + v2;
  float s2 = v0 * v0 + v1 * v1 + v2 * v2;
  #pragma unroll
  for (int m = 1; m < 64; m <<= 1) { s += __shfl_xor(s, m); s2 += __shfl_xor(s2, m); }
  __shared__ float ls[4], ls2[4];
  int w = t >> 6;
  if ((t & 63) == 0) { ls[w] = s; ls2[w] = s2; }
  __syncthreads();
  s = ls[0] + ls[1] + ls[2] + ls[3];
  s2 = ls2[0] + ls2[1] + ls2[2] + ls2[3];
  float mu = s * (1.0f / EMB);
  float var = s2 * (1.0f / EMB) - mu * mu;
  float rs = rsqrtf(var + 1e-5f);
  size_t base = (size_t)row * EMB;
  float vv[3] = { v0, v1, v2 };
  #pragma unroll
  for (int i = 0; i < 3; ++i) {
    int e = t + i * 256;
    float xn = (vv[i] - mu) * rs * g[e] + bb[e];
    u16 h = f2bf(xn);
    xn_hi[base + e] = h;
    xn_lo[base + e] = f2bf(xn - bf2f(h));
  }
}

// ---------------- Kernel 2: QKV GEMM (pre-split W) ----------------
// grid (32 row-tiles, 18 col-tiles, 2 modals), 256 thr. Tile 128x128, BK=32.
__global__ __launch_bounds__(256) void k_qkv(
    const u16* __restrict__ xn_hi, const u16* __restrict__ xn_lo,
    const u16* __restrict__ wqh, const u16* __restrict__ wql,
    const float* __restrict__ bq1, const float* __restrict__ bq2,
    u16* __restrict__ q_hi, u16* __restrict__ q_lo,
    u16* __restrict__ k_hi, u16* __restrict__ k_lo,
    u16* __restrict__ vT)
{
  int mt = blockIdx.x, ntile = blockIdx.y, modal = blockIdx.z;
  const float* BQ = modal ? bq2 : bq1;
  int typ = ntile / 6;            // 0=q 1=k 2=v
  int hd0 = (ntile % 6) * 128;

  __shared__ u16 As_hi[128 * LDA], As_lo[128 * LDA], Wh[128 * LDA], Wl[128 * LDA];

  int tid = threadIdx.x, lane = tid & 63, w = tid >> 6;
  int wm = (w >> 1) * 64, wn = (w & 1) * 64;
  int lc = lane & 15, lq = lane >> 4;

  floatx4 acc[4][4] = {};
  size_t arow0 = (size_t)(modal * RPM + mt * 128) * EMB;
  size_t wrow0 = (size_t)(modal * 2304 + typ * 768 + hd0) * EMB;

  for (int k0 = 0; k0 < EMB; k0 += 32) {
    #pragma unroll
    for (int i = 0; i < 2; ++i) {
      int c = tid + i * 256;            // 128 rows x 4 chunks of 8
      int rr = c >> 2, cc = (c & 3) * 8;
      size_t go = (size_t)rr * EMB + k0 + cc;
      *(shortx8*)&As_hi[rr * LDA + cc] = *(const shortx8*)(xn_hi + arow0 + go);
      *(shortx8*)&Wh[rr * LDA + cc]    = *(const shortx8*)(wqh + wrow0 + go);
      if (typ != 2) {
        *(shortx8*)&As_lo[rr * LDA + cc] = *(const shortx8*)(xn_lo + arow0 + go);
        *(shortx8*)&Wl[rr * LDA + cc]    = *(const shortx8*)(wql + wrow0 + go);
      }
    }
    __syncthreads();
    shortx8 ah[4], al[4], wh[4], wl[4];
    #pragma unroll
    for (int i = 0; i < 4; ++i) {
      ah[i] = *(const shortx8*)&As_hi[(wm + i * 16 + lc) * LDA + lq * 8];
      wh[i] = *(const shortx8*)&Wh[(wn + i * 16 + lc) * LDA + lq * 8];
      if (typ != 2) {
        al[i] = *(const shortx8*)&As_lo[(wm + i * 16 + lc) * LDA + lq * 8];
        wl[i] = *(const shortx8*)&Wl[(wn + i * 16 + lc) * LDA + lq * 8];
      }
    }
    #pragma unroll
    for (int i = 0; i < 4; ++i)
      #pragma unroll
      for (int jn = 0; jn < 4; ++jn) {
        acc[i][jn] = __builtin_amdgcn_mfma_f32_16x16x32_bf16(ah[i], wh[jn], acc[i][jn], 0, 0, 0);
        if (typ != 2) {
          acc[i][jn] = __builtin_amdgcn_mfma_f32_16x16x32_bf16(al[i], wh[jn], acc[i][jn], 0, 0, 0);
          acc[i][jn] = __builtin_amdgcn_mfma_f32_16x16x32_bf16(ah[i], wl[jn], acc[i][jn], 0, 0, 0);
        }
      }
    __syncthreads();
  }

  #pragma unroll
  for (int i = 0; i < 4; ++i) {
    int mrow0 = mt * 128 + wm + i * 16 + lq * 4;
    #pragma unroll
    for (int jn = 0; jn < 4; ++jn) {
      int colp = hd0 + wn + jn * 16 + lc;          // hd index [0,768)
      int h = colp >> 6, d = colp & 63;
      float bias = BQ[colp * 3 + typ];
      #pragma unroll
      for (int r = 0; r < 4; ++r) {
        int mrow = mrow0 + r;
        int b = mrow >> 11, nq = mrow & (SEQ - 1);
        int uu = modal * 24 + b * 12 + h;
        float val = acc[i][jn][r] + bias;
        if (typ == 0) {
          size_t o = ((size_t)uu * SEQ + nq) * HDIM + d;
          u16 hh = f2bf(val); q_hi[o] = hh; q_lo[o] = f2bf(val - bf2f(hh));
        } else if (typ == 1) {
          size_t o = ((size_t)uu * SEQ + nq) * HDIM + d;
          u16 hh = f2bf(val); k_hi[o] = hh; k_lo[o] = f2bf(val - bf2f(hh));
        } else {
          vT[((size_t)uu * HDIM + d) * SEQ + nq] = f2bf(val);
        }
      }
    }
  }
}

// ---------------- Kernel 3: flash attention, 128 q-rows/block ----------------
// grid (16 q-tiles, 48 units), 256 thr. Wave owns 32 q-rows (2 m-tiles); K-chunk 64.
__global__ __launch_bounds__(256) void k_attn(
    const u16* __restrict__ q_hi, const u16* __restrict__ q_lo,
    const u16* __restrict__ k_hi, const u16* __restrict__ k_lo,
    const u16* __restrict__ vT, u16* __restrict__ attn_out)
{
  int qt = blockIdx.x, u = blockIdx.y;
  __shared__ u16 Kh[64 * LDK], Kl[64 * LDK], Vs[64 * LDK];
  __shared__ u16 Ps[4][32 * LDK];

  int tid = threadIdx.x, lane = tid & 63, w = tid >> 6;
  int lc = lane & 15, lq = lane >> 4;
  u16* psw = &Ps[w][0];

  // Q fragments: 2 m-tiles x 2 k-slices, hi+lo
  shortx8 qh[2][2], ql[2][2];
  #pragma unroll
  for (int mi = 0; mi < 2; ++mi) {
    size_t qb = ((size_t)u * SEQ + qt * 128 + w * 32 + mi * 16 + lc) * HDIM + lq * 8;
    qh[mi][0] = *(const shortx8*)(q_hi + qb);
    qh[mi][1] = *(const shortx8*)(q_hi + qb + 32);
    ql[mi][0] = *(const shortx8*)(q_lo + qb);
    ql[mi][1] = *(const shortx8*)(q_lo + qb + 32);
  }

  shortx8 ONES;
  #pragma unroll
  for (int j = 0; j < 8; ++j) ONES[j] = (short)0x3F80;  // bf16 1.0

  floatx4 O[2][4] = {};
  floatx4 Osum[2] = {};
  float mrow[2][4];
  #pragma unroll
  for (int mi = 0; mi < 2; ++mi)
    #pragma unroll
    for (int r = 0; r < 4; ++r) mrow[mi][r] = -1e30f;
  const float Cs = 11.5415603271f;  // 8 * log2(e)

  // staging source pointers (thread-fixed offsets)
  int c0 = tid, c1 = tid + 256;
  int r0 = c0 >> 3, cc0 = (c0 & 7) * 8;
  int r1 = c1 >> 3, cc1 = (c1 & 7) * 8;
  const u16* khp0 = k_hi + ((size_t)u * SEQ + r0) * HDIM + cc0;
  const u16* khp1 = k_hi + ((size_t)u * SEQ + r1) * HDIM + cc1;
  const u16* klp0 = k_lo + ((size_t)u * SEQ + r0) * HDIM + cc0;
  const u16* klp1 = k_lo + ((size_t)u * SEQ + r1) * HDIM + cc1;
  const u16* vp0  = vT + ((size_t)u * HDIM + r0) * SEQ + cc0;
  const u16* vp1  = vT + ((size_t)u * HDIM + r1) * SEQ + cc1;

  for (int kc = 0; kc < SEQ; kc += 64) {
    *(shortx8*)&Kh[r0 * LDK + cc0] = *(const shortx8*)(khp0 + (size_t)kc * HDIM);
    *(shortx8*)&Kh[r1 * LDK + cc1] = *(const shortx8*)(khp1 + (size_t)kc * HDIM);
    *(shortx8*)&Kl[r0 * LDK + cc0] = *(const shortx8*)(klp0 + (size_t)kc * HDIM);
    *(shortx8*)&Kl[r1 * LDK + cc1] = *(const shortx8*)(klp1 + (size_t)kc * HDIM);
    *(shortx8*)&Vs[r0 * LDK + cc0] = *(const shortx8*)(vp0 + kc);
    *(shortx8*)&Vs[r1 * LDK + cc1] = *(const shortx8*)(vp1 + kc);
    __syncthreads();

    // S = 8*log2e * (Q.K^T), 3-pass hi/lo
    floatx4 S[2][4] = {};
    #pragma unroll
    for (int nt = 0; nt < 4; ++nt)
      #pragma unroll
      for (int ks = 0; ks < 2; ++ks) {
        shortx8 kf = *(const shortx8*)&Kh[(nt * 16 + lc) * LDK + ks * 32 + lq * 8];
        shortx8 lf = *(const shortx8*)&Kl[(nt * 16 + lc) * LDK + ks * 32 + lq * 8];
        #pragma unroll
        for (int mi = 0; mi < 2; ++mi) {
          S[mi][nt] = __builtin_amdgcn_mfma_f32_16x16x32_bf16(qh[mi][ks], kf, S[mi][nt], 0, 0, 0);
          S[mi][nt] = __builtin_amdgcn_mfma_f32_16x16x32_bf16(ql[mi][ks], kf, S[mi][nt], 0, 0, 0);
          S[mi][nt] = __builtin_amdgcn_mfma_f32_16x16x32_bf16(qh[mi][ks], lf, S[mi][nt], 0, 0, 0);
        }
      }
    #pragma unroll
    for (int mi = 0; mi < 2; ++mi)
      #pragma unroll
      for (int nt = 0; nt < 4; ++nt) S[mi][nt] *= Cs;

    // online softmax; l tracked via ones-column MFMA (Osum)
    #pragma unroll
    for (int mi = 0; mi < 2; ++mi) {
      float alpha[4];
      #pragma unroll
      for (int r = 0; r < 4; ++r) {
        float mc = fmaxf(fmaxf(S[mi][0][r], S[mi][1][r]), fmaxf(S[mi][2][r], S[mi][3][r]));
        mc = swz_max16(mc);
        float mn = fmaxf(mrow[mi][r], mc);
        alpha[r] = __builtin_amdgcn_exp2f(mrow[mi][r] - mn);
        mrow[mi][r] = mn;
      }
      #pragma unroll
      for (int nt = 0; nt < 4; ++nt)
        #pragma unroll
        for (int r = 0; r < 4; ++r) {
          float e = __builtin_amdgcn_exp2f(S[mi][nt][r] - mrow[mi][r]);
          psw[(mi * 16 + lq * 4 + r) * LDK + nt * 16 + lc] = f2bf_tr(e);
        }
      #pragma unroll
      for (int nt = 0; nt < 4; ++nt)
        #pragma unroll
        for (int r = 0; r < 4; ++r) O[mi][nt][r] *= alpha[r];
      #pragma unroll
      for (int r = 0; r < 4; ++r) Osum[mi][r] *= alpha[r];
    }

    // PV (Ps is wave-private: no barrier needed between write and read)
    #pragma unroll
    for (int ks = 0; ks < 2; ++ks) {
      shortx8 pf[2];
      #pragma unroll
      for (int mi = 0; mi < 2; ++mi)
        pf[mi] = *(const shortx8*)&psw[(mi * 16 + lc) * LDK + ks * 32 + lq * 8];
      #pragma unroll
      for (int nt = 0; nt < 4; ++nt) {
        shortx8 vf = *(const shortx8*)&Vs[(nt * 16 + lc) * LDK + ks * 32 + lq * 8];
        #pragma unroll
        for (int mi = 0; mi < 2; ++mi)
          O[mi][nt] = __builtin_amdgcn_mfma_f32_16x16x32_bf16(pf[mi], vf, O[mi][nt], 0, 0, 0);
      }
      #pragma unroll
      for (int mi = 0; mi < 2; ++mi)
        Osum[mi] = __builtin_amdgcn_mfma_f32_16x16x32_bf16(pf[mi], ONES, Osum[mi], 0, 0, 0);
    }
    __syncthreads();
  }

  int modal = u / 24, b = (u / 12) & 1, h = u % 12;
  #pragma unroll
  for (int mi = 0; mi < 2; ++mi)
    #pragma unroll
    for (int r = 0; r < 4; ++r) {
      float rl = __builtin_amdgcn_rcpf(Osum[mi][r]);
      int qrow = qt * 128 + w * 32 + mi * 16 + lq * 4 + r;
      size_t ob = ((size_t)(modal * RPM + b * SEQ + qrow)) * EMB + h * 64 + lc;
      #pragma unroll
      for (int nt = 0; nt < 4; ++nt)
        attn_out[ob + nt * 16] = f2bf(O[mi][nt][r] * rl);
    }
}

// ---------------- Kernel 4: proj GEMM (pre-split W) + bias + fp32 residual ----------------
// grid (32 row-tiles, 6 col-tiles, 2 modals)
__global__ __launch_bounds__(256) void k_proj(
    const u16* __restrict__ ao, const u16* __restrict__ wph,
    const float* __restrict__ x1, const float* __restrict__ x2,
    const float* __restrict__ bp1, const float* __restrict__ bp2,
    float* __restrict__ out)
{
  int mt = blockIdx.x, ntile = blockIdx.y, modal = blockIdx.z;
  const float* BP = modal ? bp2 : bp1;
  const float* x  = modal ? x2 : x1;

  __shared__ u16 As[128 * LDA], Ws[128 * LDA];
  int tid = threadIdx.x, lane = tid & 63, w = tid >> 6;
  int wm = (w >> 1) * 64, wn = (w & 1) * 64;
  int lc = lane & 15, lq = lane >> 4;

  floatx4 acc[4][4] = {};
  size_t arow0 = (size_t)(modal * RPM + mt * 128) * EMB;
  int col0 = ntile * 128;
  size_t wrow0 = (size_t)(modal * 768 + col0) * EMB;

  for (int k0 = 0; k0 < EMB; k0 += 32) {
    #pragma unroll
    for (int i = 0; i < 2; ++i) {
      int c = tid + i * 256;
      int rr = c >> 2, cc = (c & 3) * 8;
      size_t go = (size_t)rr * EMB + k0 + cc;
      *(shortx8*)&As[rr * LDA + cc] = *(const shortx8*)(ao + arow0 + go);
      *(shortx8*)&Ws[rr * LDA + cc] = *(const shortx8*)(wph + wrow0 + go);
    }
    __syncthreads();
    shortx8 af[4], wf[4];
    #pragma unroll
    for (int i = 0; i < 4; ++i) {
      af[i] = *(const shortx8*)&As[(wm + i * 16 + lc) * LDA + lq * 8];
      wf[i] = *(const shortx8*)&Ws[(wn + i * 16 + lc) * LDA + lq * 8];
    }
    #pragma unroll
    for (int i = 0; i < 4; ++i)
      #pragma unroll
      for (int jn = 0; jn < 4; ++jn)
        acc[i][jn] = __builtin_amdgcn_mfma_f32_16x16x32_bf16(af[i], wf[jn], acc[i][jn], 0, 0, 0);
    __syncthreads();
  }

  #pragma unroll
  for (int i = 0; i < 4; ++i) {
    int mrow0 = mt * 128 + wm + i * 16 + lq * 4;
    #pragma unroll
    for (int jn = 0; jn < 4; ++jn) {
      int col = col0 + wn + jn * 16 + lc;
      float bias = BP[col];
      #pragma unroll
      for (int r = 0; r < 4; ++r) {
        int mrow = mrow0 + r;
        float val = acc[i][jn][r] + bias + x[(size_t)mrow * EMB + col];
        out[((size_t)(modal * RPM + mrow)) * EMB + col] = val;
      }
    }
  }
}

extern "C" void kernel_launch(void* const* d_in, const int* in_sizes, int n_in,
                              void* d_out, int out_size, void* d_ws, size_t ws_size,
                              hipStream_t stream) {
  const float* modal1 = (const float*)d_in[0];
  const float* modal2 = (const float*)d_in[1];
  const float* ln1_g  = (const float*)d_in[2];
  const float* ln1_b  = (const float*)d_in[3];
  const float* w_qkv1 = (const float*)d_in[4];
  const float* b_qkv1 = (const float*)d_in[5];
  const float* w_proj1= (const float*)d_in[6];
  const float* b_proj1= (const float*)d_in[7];
  const float* ln2_g  = (const float*)d_in[8];
  const float* ln2_b  = (const float*)d_in[9];
  const float* w_qkv2 = (const float*)d_in[10];
  const float* b_qkv2 = (const float*)d_in[11];
  const float* w_proj2= (const float*)d_in[12];
  const float* b_proj2= (const float*)d_in[13];
  float* out = (float*)d_out;

  const size_t BUFE = (size_t)NROW * EMB;       // 6291456 elems
  const size_t WQE  = (size_t)2 * 2304 * EMB;   // 3538944 elems
  u16* xn_hi = (u16*)d_ws;
  u16* xn_lo = xn_hi + BUFE;
  u16* q_hi  = xn_lo + BUFE;
  u16* q_lo  = q_hi + BUFE;
  u16* k_hi  = q_lo + BUFE;
  u16* k_lo  = k_hi + BUFE;
  u16* vT    = k_lo + BUFE;
  u16* wq_h  = vT + BUFE;
  u16* wq_l  = wq_h + WQE;
  u16* attn  = xn_hi;   // xn dead after k_qkv
  u16* wp_h  = q_lo;    // q_lo dead after k_attn (w_proj needs 1.18M < 6.29M elems)

  prep_wq<<<4608, 256, 0, stream>>>(w_qkv1, w_qkv2, wq_h, wq_l);
  k_ln<<<NROW, 256, 0, stream>>>(modal1, modal2, ln1_g, ln1_b, ln2_g, ln2_b, xn_hi, xn_lo);
  dim3 g2(32, 18, 2);
  k_qkv<<<g2, 256, 0, stream>>>(xn_hi, xn_lo, wq_h, wq_l, b_qkv1, b_qkv2,
                                q_hi, q_lo, k_hi, k_lo, vT);
  dim3 g3(16, 48);
  k_attn<<<g3, 256, 0, stream>>>(q_hi, q_lo, k_hi, k_lo, vT, attn);
  prep_wp<<<1536, 256, 0, stream>>>(w_proj1, w_proj2, wp_h);
  dim3 g4(32, 6, 2);
  k_proj<<<g4, 256, 0, stream>>>(attn, wp_h, modal1, modal2, b_proj1, b_proj2, out);
}